// Round 7
// baseline (312.493 us; speedup 1.0000x reference)
//
#include <hip/hip_runtime.h>
#include <hip/hip_bf16.h>
#include <cstdint>

typedef __bf16 bf16;
typedef __bf16 bf16x8 __attribute__((ext_vector_type(8)));
typedef __bf16 bf16x4 __attribute__((ext_vector_type(4)));
typedef float f32x4 __attribute__((ext_vector_type(4)));

__device__ inline bf16x8 cvt8(const float* __restrict__ p) {
  float4 a = *(const float4*)p;
  float4 b = *(const float4*)(p + 4);
  bf16x8 r;
  r[0] = (bf16)a.x; r[1] = (bf16)a.y; r[2] = (bf16)a.z; r[3] = (bf16)a.w;
  r[4] = (bf16)b.x; r[5] = (bf16)b.y; r[6] = (bf16)b.z; r[7] = (bf16)b.w;
  return r;
}

// async global->LDS, 16B per lane; LDS dest = wave-uniform base + lane*16 (m97/m104)
__device__ inline void gl_lds16(const bf16* g, bf16* l) {
  auto gp = reinterpret_cast<const __attribute__((address_space(1))) uint32_t*>(
      reinterpret_cast<uintptr_t>(g));
  auto lp = reinterpret_cast<__attribute__((address_space(3))) uint32_t*>(
      reinterpret_cast<uintptr_t>(l));
  __builtin_amdgcn_global_load_lds(gp, lp, 16, 0, 0);
}

// ---------------------------------------------------------------- fp32 -> bf16 cast
__global__ __launch_bounds__(256) void cast_k(const float* __restrict__ in,
                                              bf16* __restrict__ out) {
  long i = ((long)blockIdx.x * 256 + threadIdx.x) * 8;
  *(bf16x8*)(out + i) = cvt8(in + i);
}

// ---------------------------------------------------------------- transpose + fp32->bf16 cast
__global__ __launch_bounds__(256) void transpose_cast_k(const float* __restrict__ in,
                                                        bf16* __restrict__ out,
                                                        int R, int C) {
  __shared__ bf16 T[32][33];
  int tc = blockIdx.x * 32, tr = blockIdx.y * 32;
  int c = threadIdx.x & 31, r8 = threadIdx.x >> 5;
#pragma unroll
  for (int i = 0; i < 4; i++) {
    int r = r8 + i * 8;
    T[r][c] = (bf16)in[(long)(tr + r) * C + tc + c];
  }
  __syncthreads();
#pragma unroll
  for (int i = 0; i < 4; i++) {
    int r = r8 + i * 8;
    out[(long)(tc + r) * R + tr + c] = T[c][r];
  }
}

// ---------------------------------------------------------------- GEMM (A MxK bf16, Bt NxK bf16)
// m97 structure: BK=32, unpadded 128x32 LDS tiles staged via global_load_lds_dwordx4.
// EPI==0: A = xb; epilogue fuses QK prep (bias+RMSNorm+RoPE+l2+scale) for q/k regions
//         (wave-complete 128B row writes) and stores v in 4-token-grouped layout
//         v4[(bh*256 + tok/4)*256... ] via packed coalesced bf16x4 stores (r6 post-mortem:
//         2B/2KB-stride scatter caused ~97MB of L2 partial-line RMW traffic).
// EPI==1: A = attention-out in (b,h,tok,d) layout (qb buffer), remapped loads; fp32 C write
template <int EPI>
__global__ __launch_bounds__(256, 5) void gemm_bt(const bf16* __restrict__ A,
                                                  const bf16* __restrict__ Bt,
                                                  const float* __restrict__ bias,
                                                  int M, int N, int K,
                                                  float* __restrict__ out,
                                                  bf16* __restrict__ qb,
                                                  bf16* __restrict__ kb,
                                                  bf16* __restrict__ v4,
                                                  const float* __restrict__ qg,
                                                  const float* __restrict__ kg) {
  __shared__ __align__(16) bf16 As[128][32];  // 64B row stride, unpadded (DMA layout)
  __shared__ __align__(16) bf16 Bs[128][32];

  const int tid = threadIdx.x;
  const int lane = tid & 63;
  const int w = tid >> 6;
  const int wm = (w & 1) * 64;
  const int wn = (w >> 1) * 64;
  const int quad = lane >> 4;
  const int l16 = lane & 15;

  const int m0 = blockIdx.y * 128;
  const int n0 = blockIdx.x * 128;

  // staging map: wave w covers rows [w*32, w*32+32) in two 1024B DMA calls;
  // lane -> row = base + (lane>>2), col = (lane&3)*8  => LDS offset = lane*16
  const int sr = w * 32 + (lane >> 2);
  const int sc = (lane & 3) * 8;

  f32x4 acc[4][4];
#pragma unroll
  for (int i = 0; i < 4; i++)
#pragma unroll
    for (int j = 0; j < 4; j++) acc[i][j] = f32x4{0.f, 0.f, 0.f, 0.f};

  for (int k0 = 0; k0 < K; k0 += 32) {
    __syncthreads();
    const bf16 *ga0, *ga1;
    if (EPI == 0) {
      ga0 = A + (long)(m0 + sr) * K + k0 + sc;
      ga1 = ga0 + (long)16 * K;
    } else {
      // A row m, col k -> ((b*16+h)*1024+tok)*64+dc ; h=k0>>6 (uniform over the 32-k tile)
      int hh = k0 >> 6, dc = (k0 & 63) + sc;
      int m1 = m0 + sr, m2 = m1 + 16;
      ga0 = A + ((long)((m1 >> 10) * 16 + hh) * 1024 + (m1 & 1023)) * 64 + dc;
      ga1 = A + ((long)((m2 >> 10) * 16 + hh) * 1024 + (m2 & 1023)) * 64 + dc;
    }
    gl_lds16(ga0, &As[w * 32][0]);
    gl_lds16(ga1, &As[w * 32 + 16][0]);
    gl_lds16(Bt + (long)(n0 + sr) * K + k0 + sc, &Bs[w * 32][0]);
    gl_lds16(Bt + (long)(n0 + sr + 16) * K + k0 + sc, &Bs[w * 32 + 16][0]);
    __syncthreads();  // compiler emits s_waitcnt vmcnt(0) before s_barrier

    bf16x8 af[4], bfr[4];
#pragma unroll
    for (int i = 0; i < 4; i++) {
      af[i] = *(const bf16x8*)&As[wm + i * 16 + l16][quad * 8];
      bfr[i] = *(const bf16x8*)&Bs[wn + i * 16 + l16][quad * 8];
    }
#pragma unroll
    for (int i = 0; i < 4; i++)
#pragma unroll
      for (int j = 0; j < 4; j++)
        acc[i][j] = __builtin_amdgcn_mfma_f32_16x16x32_bf16(af[i], bfr[j], acc[i][j], 0, 0, 0);
  }

  // ---------------- epilogue: C[row=quad*4+r][col=l16] per frag (m89/m91 layout)
  if (EPI == 1) {
#pragma unroll
    for (int i = 0; i < 4; i++)
#pragma unroll
      for (int j = 0; j < 4; j++)
#pragma unroll
        for (int r = 0; r < 4; r++) {
          int mg = m0 + wm + i * 16 + quad * 4 + r;
          int ng = n0 + wn + j * 16 + l16;
          out[(long)mg * N + ng] = acc[i][j][r] + bias[ng];
        }
    return;
  }

  const int which = n0 >> 10;  // 0=q, 1=k, 2=v (128 | 1024 so block is in one region)
  if (which == 2) {
    // v: packed coalesced store into v4(bh, tok/4, d, tok%4); lane's 4 r-values are
    // 4 consecutive tokens of one channel -> one 8B store; 16 l16 lanes -> 128B contiguous
    const int T0 = (((m0 & 1023) + wm) >> 2) + quad;  // tokg for this lane, +4 per i
#pragma unroll
    for (int i = 0; i < 4; i++) {
#pragma unroll
      for (int j = 0; j < 4; j++) {
        int ng = n0 + wn + j * 16 + l16;
        int rem = ng & 1023, head = rem >> 6, dc = rem & 63;
        int bh = (m0 >> 10) * 16 + head;
        float bj = bias[ng];
        bf16x4 pv;
#pragma unroll
        for (int r = 0; r < 4; r++) pv[r] = (bf16)(acc[i][j][r] + bj);
        *(bf16x4*)(v4 + ((long)bh * 16384 + (long)(T0 + i * 4) * 64 + dc) * 4) = pv;
      }
    }
    return;
  }

  // q/k: fused bias + RMSNorm + 2D RoPE + l2-normalize (+8x fold for q).
  // This wave's 4 j-frags hold channels ch = j*16+l16 of ONE head:
  const float* gg = which ? kg : qg;
  bf16* dst = which ? kb : qb;
  const float fold = which ? 1.0f : 8.0f;
  const int h = ((n0 + wn) & 1023) >> 6;
  const int bh = (m0 >> 10) * 16 + h;
  float bj[4], gain[4];
#pragma unroll
  for (int j = 0; j < 4; j++) {
    bj[j] = bias[n0 + wn + j * 16 + l16];
    gain[j] = gg[j * 16 + l16];
  }
  const float f = exp2f((float)l16 * (-13.287712379549449f / 16.0f));  // 10000^(-l16/16)

#pragma unroll
  for (int i = 0; i < 4; i++) {
#pragma unroll
    for (int r = 0; r < 4; r++) {
      int ntok = (m0 & 1023) + wm + i * 16 + quad * 4 + r;
      float v0 = acc[i][0][r] + bj[0];
      float v1 = acc[i][1][r] + bj[1];
      float v2 = acc[i][2][r] + bj[2];
      float v3 = acc[i][3][r] + bj[3];
      // RMSNorm over d=64 (reduce over the 16 l16 lanes; each holds 4 channels)
      float ss = v0 * v0 + v1 * v1 + v2 * v2 + v3 * v3;
#pragma unroll
      for (int m = 1; m <= 8; m <<= 1) ss += __shfl_xor(ss, m, 64);
      float rms = rsqrtf(ss * (1.0f / 64.0f) + 1e-6f);
      v0 *= rms * gain[0]; v1 *= rms * gain[1]; v2 *= rms * gain[2]; v3 *= rms * gain[3];
      // 2D axial RoPE: ch<32 angle = pos*freq (h for ch<16, w for 16..31); partner ch±32
      float sh, ch_, swv, cw;
      __sincosf((float)(ntok >> 5) * f, &sh, &ch_);
      __sincosf((float)(ntok & 31) * f, &swv, &cw);
      float w0 = v0 * ch_ - v2 * sh;
      float w1 = v1 * cw - v3 * swv;
      float w2 = v2 * ch_ + v0 * sh;
      float w3 = v3 * cw + v1 * swv;
      // l2 normalize (+ cosine-sim scale fold)
      float nn = w0 * w0 + w1 * w1 + w2 * w2 + w3 * w3;
#pragma unroll
      for (int m = 1; m <= 8; m <<= 1) nn += __shfl_xor(nn, m, 64);
      float inv = rsqrtf(nn) * fold;
      long base = ((long)bh * 1024 + ntok) * 64 + l16;
      dst[base] = (bf16)(w0 * inv);
      dst[base + 16] = (bf16)(w1 * inv);
      dst[base + 32] = (bf16)(w2 * inv);
      dst[base + 48] = (bf16)(w3 * inv);
    }
  }
}

// ---------------------------------------------------------------- flash attention (fixed-max softmax)
// s = 8*cos in [-8,8] -> p = exp(s-8); S^T = K·Q^T so lane's C-column is one query.
// V tile (8KB, contiguous in the v4 grouped layout) staged via global_load_lds DMA.
// block = (bh, 64-query tile); wave = 16 queries; K-tile = 64 keys. O overwrites qb in-place.
__global__ __launch_bounds__(256) void attn_k(bf16* __restrict__ qb,
                                              const bf16* __restrict__ kb,
                                              const bf16* __restrict__ v4) {
  __shared__ __align__(16) bf16 Ks[64][72];     // keys x d (manual staging, padded)
  __shared__ __align__(16) bf16 Vl[4096];       // linear v4 tile: (tokg, d, t) t=key%4
  __shared__ __align__(16) bf16 Ps[4][16][72];  // per-wave P[q][key]

  const int tid = threadIdx.x;
  const int lane = tid & 63;
  const int w = tid >> 6;
  const int quad = lane >> 4;
  const int l16 = lane & 15;

  const int bh = blockIdx.y;
  const int q0 = blockIdx.x * 64 + w * 16;

  const long qrow = ((long)bh * 1024 + q0 + l16) * 64;
  bf16x8 aq0 = *(const bf16x8*)(qb + qrow + quad * 8);
  bf16x8 aq1 = *(const bf16x8*)(qb + qrow + 32 + quad * 8);

  f32x4 o[4];
#pragma unroll
  for (int i = 0; i < 4; i++) o[i] = f32x4{0.f, 0.f, 0.f, 0.f};
  float lsum = 0.0f;

  const int sr = tid >> 3, sc = (tid & 7) * 8;  // K staging: 32 rows x 64 cols per pass
  const bf16* kbase = kb + (long)bh * 65536;
  const bf16* vbase = v4 + (long)bh * 65536;

  for (int kt = 0; kt < 1024; kt += 64) {
    __syncthreads();
    *(bf16x8*)&Ks[sr][sc]      = *(const bf16x8*)(kbase + (long)(kt + sr) * 64 + sc);
    *(bf16x8*)&Ks[sr + 32][sc] = *(const bf16x8*)(kbase + (long)(kt + sr + 32) * 64 + sc);
    // V: 8KB contiguous tile -> 8 DMA calls (2 per wave), linear LDS
    gl_lds16(vbase + (long)kt * 64 + (w * 2) * 512 + lane * 8, &Vl[(w * 2) * 512]);
    gl_lds16(vbase + (long)kt * 64 + (w * 2 + 1) * 512 + lane * 8, &Vl[(w * 2 + 1) * 512]);
    __syncthreads();

    // St = K_tile · Q^T (64 keys x 16 q); frag i: key = i*16+quad*4+r, q = l16
#pragma unroll
    for (int i = 0; i < 4; i++) {
      f32x4 st = f32x4{0.f, 0.f, 0.f, 0.f};
      bf16x8 kf0 = *(const bf16x8*)&Ks[i * 16 + l16][quad * 8];
      bf16x8 kf1 = *(const bf16x8*)&Ks[i * 16 + l16][32 + quad * 8];
      st = __builtin_amdgcn_mfma_f32_16x16x32_bf16(kf0, aq0, st, 0, 0, 0);
      st = __builtin_amdgcn_mfma_f32_16x16x32_bf16(kf1, aq1, st, 0, 0, 0);
      bf16x4 pk;
#pragma unroll
      for (int r = 0; r < 4; r++) {
        float p = __expf(st[r] - 8.0f);
        lsum += p;
        pk[r] = (bf16)p;
      }
      *(bf16x4*)&Ps[w][l16][i * 16 + quad * 4] = pk;
    }
    asm volatile("s_waitcnt lgkmcnt(0)" ::: "memory");

    bf16x8 bp0 = *(const bf16x8*)&Ps[w][l16][quad * 8];
    bf16x8 bp1 = *(const bf16x8*)&Ps[w][l16][32 + quad * 8];

    // O^T += V^T_tile · P ; A-frag (d=i*16+l16, keys quad*8..+7) from Vl:
    // keys 8q..8q+3 at tokg=2q (offset 512q + 4d), keys +4..+7 at tokg=2q+1 (+256)
#pragma unroll
    for (int i = 0; i < 4; i++) {
      int D4 = (i * 16 + l16) * 4;
      bf16x4 a0 = *(const bf16x4*)&Vl[quad * 512 + D4];
      bf16x4 a1 = *(const bf16x4*)&Vl[quad * 512 + D4 + 256];
      bf16x4 a2 = *(const bf16x4*)&Vl[quad * 512 + D4 + 2048];
      bf16x4 a3 = *(const bf16x4*)&Vl[quad * 512 + D4 + 2048 + 256];
      bf16x8 vf0 = __builtin_shufflevector(a0, a1, 0, 1, 2, 3, 4, 5, 6, 7);
      bf16x8 vf1 = __builtin_shufflevector(a2, a3, 0, 1, 2, 3, 4, 5, 6, 7);
      o[i] = __builtin_amdgcn_mfma_f32_16x16x32_bf16(vf0, bp0, o[i], 0, 0, 0);
      o[i] = __builtin_amdgcn_mfma_f32_16x16x32_bf16(vf1, bp1, o[i], 0, 0, 0);
    }
  }

  lsum += __shfl_xor(lsum, 16, 64);
  lsum += __shfl_xor(lsum, 32, 64);
  float inv = 1.0f / lsum;

#pragma unroll
  for (int i = 0; i < 4; i++) {
    bf16x4 ov;
#pragma unroll
    for (int r = 0; r < 4; r++) ov[r] = (bf16)(o[i][r] * inv);
    *(bf16x4*)(qb + qrow + i * 16 + quad * 4) = ov;
  }
}

// ---------------------------------------------------------------- launcher
extern "C" void kernel_launch(void* const* d_in, const int* in_sizes, int n_in,
                              void* d_out, int out_size, void* d_ws, size_t ws_size,
                              hipStream_t stream) {
  (void)in_sizes; (void)n_in; (void)out_size; (void)ws_size;
  const float* x     = (const float*)d_in[0];
  const float* w_qkv = (const float*)d_in[1];
  const float* b_qkv = (const float*)d_in[2];
  const float* q_g   = (const float*)d_in[3];
  const float* k_g   = (const float*)d_in[4];
  const float* w_out = (const float*)d_in[5];
  const float* b_out = (const float*)d_in[6];
  float* out = (float*)d_out;

  char* ws = (char*)d_ws;
  bf16* wqkvT = (bf16*)ws; ws += (long)3072 * 1024 * 2;      // 6 MB
  bf16* woT   = (bf16*)ws; ws += (long)1024 * 1024 * 2;      // 2 MB
  bf16* xb    = (bf16*)ws; ws += (long)8192 * 1024 * 2;      // 16 MB
  bf16* qb    = (bf16*)ws; ws += (long)128 * 1024 * 64 * 2;  // 16 MB (q, then attention O)
  bf16* kb    = (bf16*)ws; ws += (long)128 * 1024 * 64 * 2;  // 16 MB
  bf16* v4    = (bf16*)ws; ws += (long)128 * 64 * 1024 * 2;  // 16 MB   (total 72 MB)

  cast_k<<<4096, 256, 0, stream>>>(x, xb);
  transpose_cast_k<<<dim3(3072 / 32, 1024 / 32), 256, 0, stream>>>(w_qkv, wqkvT, 1024, 3072);
  transpose_cast_k<<<dim3(1024 / 32, 1024 / 32), 256, 0, stream>>>(w_out, woT, 1024, 1024);
  gemm_bt<0><<<dim3(3072 / 128, 8192 / 128), 256, 0, stream>>>(xb, wqkvT, b_qkv,
                                                               8192, 3072, 1024,
                                                               (float*)nullptr, qb, kb, v4,
                                                               q_g, k_g);
  attn_k<<<dim3(16, 128), 256, 0, stream>>>(qb, kb, v4);
  gemm_bt<1><<<dim3(1024 / 128, 8192 / 128), 256, 0, stream>>>(qb, woT, b_out,
                                                               8192, 1024, 1024,
                                                               out, (bf16*)nullptr,
                                                               (bf16*)nullptr, (bf16*)nullptr,
                                                               (const float*)nullptr,
                                                               (const float*)nullptr);
}

// Round 8
// 289.368 us; speedup vs baseline: 1.0799x; 1.0799x over previous
//
#include <hip/hip_runtime.h>
#include <hip/hip_bf16.h>
#include <cstdint>

typedef __bf16 bf16;
typedef __bf16 bf16x8 __attribute__((ext_vector_type(8)));
typedef __bf16 bf16x4 __attribute__((ext_vector_type(4)));
typedef float f32x4 __attribute__((ext_vector_type(4)));

__device__ inline bf16x8 cvt8(const float* __restrict__ p) {
  float4 a = *(const float4*)p;
  float4 b = *(const float4*)(p + 4);
  bf16x8 r;
  r[0] = (bf16)a.x; r[1] = (bf16)a.y; r[2] = (bf16)a.z; r[3] = (bf16)a.w;
  r[4] = (bf16)b.x; r[5] = (bf16)b.y; r[6] = (bf16)b.z; r[7] = (bf16)b.w;
  return r;
}

// async global->LDS, 16B per lane; LDS dest = wave-uniform base + lane*16 (m97/m104)
__device__ inline void gl_lds16(const bf16* g, bf16* l) {
  auto gp = reinterpret_cast<const __attribute__((address_space(1))) uint32_t*>(
      reinterpret_cast<uintptr_t>(g));
  auto lp = reinterpret_cast<__attribute__((address_space(3))) uint32_t*>(
      reinterpret_cast<uintptr_t>(l));
  __builtin_amdgcn_global_load_lds(gp, lp, 16, 0, 0);
}

// ---------------------------------------------------------------- fp32 -> bf16 cast
__global__ __launch_bounds__(256) void cast_k(const float* __restrict__ in,
                                              bf16* __restrict__ out) {
  long i = ((long)blockIdx.x * 256 + threadIdx.x) * 8;
  *(bf16x8*)(out + i) = cvt8(in + i);
}

// ---------------------------------------------------------------- transpose + fp32->bf16 cast
__global__ __launch_bounds__(256) void transpose_cast_k(const float* __restrict__ in,
                                                        bf16* __restrict__ out,
                                                        int R, int C) {
  __shared__ bf16 T[32][33];
  int tc = blockIdx.x * 32, tr = blockIdx.y * 32;
  int c = threadIdx.x & 31, r8 = threadIdx.x >> 5;
#pragma unroll
  for (int i = 0; i < 4; i++) {
    int r = r8 + i * 8;
    T[r][c] = (bf16)in[(long)(tr + r) * C + tc + c];
  }
  __syncthreads();
#pragma unroll
  for (int i = 0; i < 4; i++) {
    int r = r8 + i * 8;
    out[(long)(tc + r) * R + tr + c] = T[c][r];
  }
}

// ---------------------------------------------------------------- GEMM (A MxK bf16, Bt NxK bf16)
// m97 structure: BK=32, unpadded 128x32 LDS tiles staged via global_load_lds_dwordx4.
// EPI==0: A = xb; epilogue fuses QK prep (bias+RMSNorm+RoPE+l2+scale) for q/k regions
//         and stores v in 4-token-grouped layout v4(bh, tok/4, d, tok%4).
// EPI==1: A = attention-out in (b,h,tok,d) layout (qb buffer), remapped loads; fp32 C write
template <int EPI>
__global__ __launch_bounds__(256, 5) void gemm_bt(const bf16* __restrict__ A,
                                                  const bf16* __restrict__ Bt,
                                                  const float* __restrict__ bias,
                                                  int M, int N, int K,
                                                  float* __restrict__ out,
                                                  bf16* __restrict__ qb,
                                                  bf16* __restrict__ kb,
                                                  bf16* __restrict__ v4,
                                                  const float* __restrict__ qg,
                                                  const float* __restrict__ kg) {
  __shared__ __align__(16) bf16 As[128][32];  // 64B row stride, unpadded (DMA layout)
  __shared__ __align__(16) bf16 Bs[128][32];

  const int tid = threadIdx.x;
  const int lane = tid & 63;
  const int w = tid >> 6;
  const int wm = (w & 1) * 64;
  const int wn = (w >> 1) * 64;
  const int quad = lane >> 4;
  const int l16 = lane & 15;

  const int m0 = blockIdx.y * 128;
  const int n0 = blockIdx.x * 128;

  const int sr = w * 32 + (lane >> 2);
  const int sc = (lane & 3) * 8;

  f32x4 acc[4][4];
#pragma unroll
  for (int i = 0; i < 4; i++)
#pragma unroll
    for (int j = 0; j < 4; j++) acc[i][j] = f32x4{0.f, 0.f, 0.f, 0.f};

  for (int k0 = 0; k0 < K; k0 += 32) {
    __syncthreads();
    const bf16 *ga0, *ga1;
    if (EPI == 0) {
      ga0 = A + (long)(m0 + sr) * K + k0 + sc;
      ga1 = ga0 + (long)16 * K;
    } else {
      int hh = k0 >> 6, dc = (k0 & 63) + sc;
      int m1 = m0 + sr, m2 = m1 + 16;
      ga0 = A + ((long)((m1 >> 10) * 16 + hh) * 1024 + (m1 & 1023)) * 64 + dc;
      ga1 = A + ((long)((m2 >> 10) * 16 + hh) * 1024 + (m2 & 1023)) * 64 + dc;
    }
    gl_lds16(ga0, &As[w * 32][0]);
    gl_lds16(ga1, &As[w * 32 + 16][0]);
    gl_lds16(Bt + (long)(n0 + sr) * K + k0 + sc, &Bs[w * 32][0]);
    gl_lds16(Bt + (long)(n0 + sr + 16) * K + k0 + sc, &Bs[w * 32 + 16][0]);
    __syncthreads();

    bf16x8 af[4], bfr[4];
#pragma unroll
    for (int i = 0; i < 4; i++) {
      af[i] = *(const bf16x8*)&As[wm + i * 16 + l16][quad * 8];
      bfr[i] = *(const bf16x8*)&Bs[wn + i * 16 + l16][quad * 8];
    }
#pragma unroll
    for (int i = 0; i < 4; i++)
#pragma unroll
      for (int j = 0; j < 4; j++)
        acc[i][j] = __builtin_amdgcn_mfma_f32_16x16x32_bf16(af[i], bfr[j], acc[i][j], 0, 0, 0);
  }

  // ---------------- epilogue: C[row=quad*4+r][col=l16] per frag (m89/m91 layout)
  if (EPI == 1) {
#pragma unroll
    for (int i = 0; i < 4; i++)
#pragma unroll
      for (int j = 0; j < 4; j++)
#pragma unroll
        for (int r = 0; r < 4; r++) {
          int mg = m0 + wm + i * 16 + quad * 4 + r;
          int ng = n0 + wn + j * 16 + l16;
          out[(long)mg * N + ng] = acc[i][j][r] + bias[ng];
        }
    return;
  }

  const int which = n0 >> 10;  // 0=q, 1=k, 2=v
  if (which == 2) {
    const int T0 = (((m0 & 1023) + wm) >> 2) + quad;
#pragma unroll
    for (int i = 0; i < 4; i++) {
#pragma unroll
      for (int j = 0; j < 4; j++) {
        int ng = n0 + wn + j * 16 + l16;
        int rem = ng & 1023, head = rem >> 6, dc = rem & 63;
        int bh = (m0 >> 10) * 16 + head;
        float bj = bias[ng];
        bf16x4 pv;
#pragma unroll
        for (int r = 0; r < 4; r++) pv[r] = (bf16)(acc[i][j][r] + bj);
        *(bf16x4*)(v4 + ((long)bh * 16384 + (long)(T0 + i * 4) * 64 + dc) * 4) = pv;
      }
    }
    return;
  }

  // q/k: fused bias + RMSNorm + 2D RoPE + l2-normalize (+8x fold for q).
  const float* gg = which ? kg : qg;
  bf16* dst = which ? kb : qb;
  const float fold = which ? 1.0f : 8.0f;
  const int h = ((n0 + wn) & 1023) >> 6;
  const int bh = (m0 >> 10) * 16 + h;
  float bj[4], gain[4];
#pragma unroll
  for (int j = 0; j < 4; j++) {
    bj[j] = bias[n0 + wn + j * 16 + l16];
    gain[j] = gg[j * 16 + l16];
  }
  const float f = exp2f((float)l16 * (-13.287712379549449f / 16.0f));  // 10000^(-l16/16)

#pragma unroll
  for (int i = 0; i < 4; i++) {
#pragma unroll
    for (int r = 0; r < 4; r++) {
      int ntok = (m0 & 1023) + wm + i * 16 + quad * 4 + r;
      float v0 = acc[i][0][r] + bj[0];
      float v1 = acc[i][1][r] + bj[1];
      float v2 = acc[i][2][r] + bj[2];
      float v3 = acc[i][3][r] + bj[3];
      float ss = v0 * v0 + v1 * v1 + v2 * v2 + v3 * v3;
#pragma unroll
      for (int m = 1; m <= 8; m <<= 1) ss += __shfl_xor(ss, m, 64);
      float rms = rsqrtf(ss * (1.0f / 64.0f) + 1e-6f);
      v0 *= rms * gain[0]; v1 *= rms * gain[1]; v2 *= rms * gain[2]; v3 *= rms * gain[3];
      float sh, ch_, swv, cw;
      __sincosf((float)(ntok >> 5) * f, &sh, &ch_);
      __sincosf((float)(ntok & 31) * f, &swv, &cw);
      float w0 = v0 * ch_ - v2 * sh;
      float w1 = v1 * cw - v3 * swv;
      float w2 = v2 * ch_ + v0 * sh;
      float w3 = v3 * cw + v1 * swv;
      float nn = w0 * w0 + w1 * w1 + w2 * w2 + w3 * w3;
#pragma unroll
      for (int m = 1; m <= 8; m <<= 1) nn += __shfl_xor(nn, m, 64);
      float inv = rsqrtf(nn) * fold;
      long base = ((long)bh * 1024 + ntok) * 64 + l16;
      dst[base] = (bf16)(w0 * inv);
      dst[base + 16] = (bf16)(w1 * inv);
      dst[base + 32] = (bf16)(w2 * inv);
      dst[base + 48] = (bf16)(w3 * inv);
    }
  }
}

// ---------------------------------------------------------------- flash attention (fixed-max softmax)
// 64 queries per wave (4 groups of 16): K/V fragments hoisted to registers once per
// K-tile and reused across the 4 groups -> 4x less LDS fragment traffic per MFMA and
// 4x less K/V global re-read (r7 post-mortem: attn was LDS-throughput-bound).
// block = 4 waves = 256 queries; grid (4, 128) = 2 blocks/CU; VGPR ~190 ok at 2 blocks.
__global__ __launch_bounds__(256, 2) void attn_k(bf16* __restrict__ qb,
                                                 const bf16* __restrict__ kb,
                                                 const bf16* __restrict__ v4) {
  __shared__ __align__(16) bf16 Ks[64][72];     // keys x d (manual staging, padded)
  __shared__ __align__(16) bf16 Vl[4096];       // linear v4 tile: (tokg, d, t) t=key%4
  __shared__ __align__(16) bf16 Ps[4][16][72];  // per-wave P[q][key], reused per group

  const int tid = threadIdx.x;
  const int lane = tid & 63;
  const int w = tid >> 6;
  const int quad = lane >> 4;
  const int l16 = lane & 15;

  const int bh = blockIdx.y;
  const int q0 = blockIdx.x * 256 + w * 64;

  // Q fragments for 4 query groups (q already holds cos-sim scale 8)
  bf16x8 aq[4][2];
  long qrow[4];
#pragma unroll
  for (int g = 0; g < 4; g++) {
    qrow[g] = ((long)bh * 1024 + q0 + g * 16 + l16) * 64;
    aq[g][0] = *(const bf16x8*)(qb + qrow[g] + quad * 8);
    aq[g][1] = *(const bf16x8*)(qb + qrow[g] + 32 + quad * 8);
  }

  f32x4 o[4][4];
#pragma unroll
  for (int g = 0; g < 4; g++)
#pragma unroll
    for (int i = 0; i < 4; i++) o[g][i] = f32x4{0.f, 0.f, 0.f, 0.f};
  float ls[4] = {0.f, 0.f, 0.f, 0.f};

  const int sr = tid >> 3, sc = (tid & 7) * 8;  // K staging: 32 rows x 64 cols per pass
  const bf16* kbase = kb + (long)bh * 65536;
  const bf16* vbase = v4 + (long)bh * 65536;

  for (int kt = 0; kt < 1024; kt += 64) {
    __syncthreads();
    *(bf16x8*)&Ks[sr][sc]      = *(const bf16x8*)(kbase + (long)(kt + sr) * 64 + sc);
    *(bf16x8*)&Ks[sr + 32][sc] = *(const bf16x8*)(kbase + (long)(kt + sr + 32) * 64 + sc);
    gl_lds16(vbase + (long)kt * 64 + (w * 2) * 512 + lane * 8, &Vl[(w * 2) * 512]);
    gl_lds16(vbase + (long)kt * 64 + (w * 2 + 1) * 512 + lane * 8, &Vl[(w * 2 + 1) * 512]);
    __syncthreads();

    // hoist K-frags (key=i*16+..., d-halves) and V-frags (d=i*16+l16, keys quad*8..+7)
    bf16x8 kf[4][2], vf[4][2];
#pragma unroll
    for (int i = 0; i < 4; i++) {
      kf[i][0] = *(const bf16x8*)&Ks[i * 16 + l16][quad * 8];
      kf[i][1] = *(const bf16x8*)&Ks[i * 16 + l16][32 + quad * 8];
      int D4 = (i * 16 + l16) * 4;
      bf16x4 a0 = *(const bf16x4*)&Vl[quad * 512 + D4];
      bf16x4 a1 = *(const bf16x4*)&Vl[quad * 512 + D4 + 256];
      bf16x4 a2 = *(const bf16x4*)&Vl[quad * 512 + D4 + 2048];
      bf16x4 a3 = *(const bf16x4*)&Vl[quad * 512 + D4 + 2048 + 256];
      vf[i][0] = __builtin_shufflevector(a0, a1, 0, 1, 2, 3, 4, 5, 6, 7);
      vf[i][1] = __builtin_shufflevector(a2, a3, 0, 1, 2, 3, 4, 5, 6, 7);
    }

#pragma unroll
    for (int g = 0; g < 4; g++) {
      // St = K_tile · Qg^T ; p = exp(s-8); per-lane l partial (column q=l16)
#pragma unroll
      for (int i = 0; i < 4; i++) {
        f32x4 st = f32x4{0.f, 0.f, 0.f, 0.f};
        st = __builtin_amdgcn_mfma_f32_16x16x32_bf16(kf[i][0], aq[g][0], st, 0, 0, 0);
        st = __builtin_amdgcn_mfma_f32_16x16x32_bf16(kf[i][1], aq[g][1], st, 0, 0, 0);
        bf16x4 pk;
#pragma unroll
        for (int r = 0; r < 4; r++) {
          float p = __expf(st[r] - 8.0f);
          ls[g] += p;
          pk[r] = (bf16)p;
        }
        *(bf16x4*)&Ps[w][l16][i * 16 + quad * 4] = pk;
      }
      asm volatile("s_waitcnt lgkmcnt(0)" ::: "memory");
      bf16x8 bp0 = *(const bf16x8*)&Ps[w][l16][quad * 8];
      bf16x8 bp1 = *(const bf16x8*)&Ps[w][l16][32 + quad * 8];
#pragma unroll
      for (int i = 0; i < 4; i++) {
        o[g][i] = __builtin_amdgcn_mfma_f32_16x16x32_bf16(vf[i][0], bp0, o[g][i], 0, 0, 0);
        o[g][i] = __builtin_amdgcn_mfma_f32_16x16x32_bf16(vf[i][1], bp1, o[g][i], 0, 0, 0);
      }
    }
  }

#pragma unroll
  for (int g = 0; g < 4; g++) {
    float l = ls[g];
    l += __shfl_xor(l, 16, 64);
    l += __shfl_xor(l, 32, 64);
    float inv = 1.0f / l;
#pragma unroll
    for (int i = 0; i < 4; i++) {
      bf16x4 ov;
#pragma unroll
      for (int r = 0; r < 4; r++) ov[r] = (bf16)(o[g][i][r] * inv);
      *(bf16x4*)(qb + qrow[g] + i * 16 + quad * 4) = ov;
    }
  }
}

// ---------------------------------------------------------------- launcher
extern "C" void kernel_launch(void* const* d_in, const int* in_sizes, int n_in,
                              void* d_out, int out_size, void* d_ws, size_t ws_size,
                              hipStream_t stream) {
  (void)in_sizes; (void)n_in; (void)out_size; (void)ws_size;
  const float* x     = (const float*)d_in[0];
  const float* w_qkv = (const float*)d_in[1];
  const float* b_qkv = (const float*)d_in[2];
  const float* q_g   = (const float*)d_in[3];
  const float* k_g   = (const float*)d_in[4];
  const float* w_out = (const float*)d_in[5];
  const float* b_out = (const float*)d_in[6];
  float* out = (float*)d_out;

  char* ws = (char*)d_ws;
  bf16* wqkvT = (bf16*)ws; ws += (long)3072 * 1024 * 2;      // 6 MB
  bf16* woT   = (bf16*)ws; ws += (long)1024 * 1024 * 2;      // 2 MB
  bf16* xb    = (bf16*)ws; ws += (long)8192 * 1024 * 2;      // 16 MB
  bf16* qb    = (bf16*)ws; ws += (long)128 * 1024 * 64 * 2;  // 16 MB (q, then attention O)
  bf16* kb    = (bf16*)ws; ws += (long)128 * 1024 * 64 * 2;  // 16 MB
  bf16* v4    = (bf16*)ws; ws += (long)128 * 64 * 1024 * 2;  // 16 MB   (total 72 MB)

  cast_k<<<4096, 256, 0, stream>>>(x, xb);
  transpose_cast_k<<<dim3(3072 / 32, 1024 / 32), 256, 0, stream>>>(w_qkv, wqkvT, 1024, 3072);
  transpose_cast_k<<<dim3(1024 / 32, 1024 / 32), 256, 0, stream>>>(w_out, woT, 1024, 1024);
  gemm_bt<0><<<dim3(3072 / 128, 8192 / 128), 256, 0, stream>>>(xb, wqkvT, b_qkv,
                                                               8192, 3072, 1024,
                                                               (float*)nullptr, qb, kb, v4,
                                                               q_g, k_g);
  attn_k<<<dim3(4, 128), 256, 0, stream>>>(qb, kb, v4);
  gemm_bt<1><<<dim3(1024 / 128, 8192 / 128), 256, 0, stream>>>(qb, woT, b_out,
                                                               8192, 1024, 1024,
                                                               out, (bf16*)nullptr,
                                                               (bf16*)nullptr, (bf16*)nullptr,
                                                               (const float*)nullptr,
                                                               (const float*)nullptr);
}